// Round 1
// baseline (521.851 us; speedup 1.0000x reference)
//
#include <hip/hip_runtime.h>
#include <math.h>

#define B_  2
#define N_  384
#define C_  256
#define H_  4
#define D_  64
#define NBH (B_*H_)            // 8
#define TSZ (NBH*N_*D_)        // 196608 floats per projected tensor [bh][n][d]
#define ESZ (NBH*N_*N_)        // 1179648 elems per logit matrix [bh][i][j]
#define SCALE 0.125f           // D^-0.5
#define PIT 72                 // padded LDS pitch in f16 (144B) -> 2-way max bank alias
#define NWSLICE (NBH*N_*68)    // 208896 floats per numw partial

typedef _Float16 f16;
typedef f16  f16x8 __attribute__((ext_vector_type(8)));
typedef f16  f16x4 __attribute__((ext_vector_type(4)));
typedef float f32x4 __attribute__((ext_vector_type(4)));

// ---------------------------------------------------------------------------
// Kernel 1: projection (unchanged). proj[t][bh][n][d], t in {a,b,c,v1,v2}, f32.
// ---------------------------------------------------------------------------
__global__ __launch_bounds__(256) void proj_kernel(const float* __restrict__ x,
                                                   const float* __restrict__ W,
                                                   float* __restrict__ proj) {
    __shared__ float Xs[32][68];
    __shared__ float Ws[32][68];
    const int tid = threadIdx.x;
    const int tx = tid & 15, ty = tid >> 4;
    const int m0 = blockIdx.x * 64;
    const int c0 = blockIdx.y * 64;
    const int t  = c0 >> 8;
    const int wbase = ((t >= 3) ? (t + 3) : t) * 256;

    float acc[4][4] = {{0.f}};
    for (int k0 = 0; k0 < 256; k0 += 32) {
        __syncthreads();
#pragma unroll
        for (int l = 0; l < 8; ++l) {
            const int idx = l * 256 + tid;
            const int mi = idx >> 5, kk = idx & 31;
            Xs[kk][mi] = x[(m0 + mi) * 256 + k0 + kk];
            const int rem = (c0 + mi) & 255;
            Ws[kk][mi] = W[(wbase + rem) * 256 + k0 + kk];
        }
        __syncthreads();
#pragma unroll
        for (int kk = 0; kk < 32; ++kk) {
            const float4 xf = *(const float4*)&Xs[kk][ty * 4];
            const float4 wf = *(const float4*)&Ws[kk][tx * 4];
            const float xa[4] = {xf.x, xf.y, xf.z, xf.w};
            const float wa[4] = {wf.x, wf.y, wf.z, wf.w};
#pragma unroll
            for (int q = 0; q < 4; ++q)
#pragma unroll
                for (int p = 0; p < 4; ++p)
                    acc[q][p] += xa[q] * wa[p];
        }
    }
#pragma unroll
    for (int q = 0; q < 4; ++q) {
        const int r = m0 + ty * 4 + q;
        const int b = r / N_;
        const int n = r - b * N_;
#pragma unroll
        for (int p = 0; p < 4; ++p) {
            const int rem = (c0 + tx * 4 + p) & 255;
            const int h = rem >> 6, d = rem & 63;
            proj[t * TSZ + ((b * H_ + h) * N_ + n) * D_ + d] = acc[q][p];
        }
    }
}

// ---------------------------------------------------------------------------
// Kernel 2: exp-logit matrices, mixed-dtype outputs (unchanged).
// ---------------------------------------------------------------------------
__global__ __launch_bounds__(256) void logits_kernel(const float* __restrict__ proj,
                                                     f16* __restrict__ eabt16,
                                                     float* __restrict__ ecd,
                                                     f16* __restrict__ eef16) {
    __shared__ float Xs[32][68];
    __shared__ float Ys[32][68];
    const int tid = threadIdx.x;
    const int tx = tid & 15, ty = tid >> 4;
    const int i0 = blockIdx.x * 64, j0 = blockIdx.y * 64;
    const int q  = blockIdx.z >> 3;
    const int bh = blockIdx.z & 7;
    const int xt = q;
    const int yt = (q == 2) ? 0 : (q + 1);
    const float* Xp = proj + xt * TSZ + bh * N_ * D_;
    const float* Yp = proj + yt * TSZ + bh * N_ * D_;

    float acc[4][4] = {{0.f}};
    for (int k0 = 0; k0 < 64; k0 += 32) {
        __syncthreads();
#pragma unroll
        for (int l = 0; l < 8; ++l) {
            const int idx = l * 256 + tid;
            const int mi = idx >> 5, kk = idx & 31;
            Xs[kk][mi] = Xp[(i0 + mi) * 64 + k0 + kk];
            Ys[kk][mi] = Yp[(j0 + mi) * 64 + k0 + kk];
        }
        __syncthreads();
#pragma unroll
        for (int kk = 0; kk < 32; ++kk) {
            const float4 xf = *(const float4*)&Xs[kk][ty * 4];
            const float4 yf = *(const float4*)&Ys[kk][tx * 4];
            const float xa[4] = {xf.x, xf.y, xf.z, xf.w};
            const float ya[4] = {yf.x, yf.y, yf.z, yf.w};
#pragma unroll
            for (int qq = 0; qq < 4; ++qq)
#pragma unroll
                for (int p = 0; p < 4; ++p)
                    acc[qq][p] += xa[qq] * ya[p];
        }
    }
#pragma unroll
    for (int qq = 0; qq < 4; ++qq)
#pragma unroll
        for (int p = 0; p < 4; ++p) {
            const float e = expf(acc[qq][p] * SCALE);
            const int ii = i0 + ty * 4 + qq;
            const int jj = j0 + tx * 4 + p;
            if (q == 0)      eabt16[(size_t)bh * N_ * N_ + jj * N_ + ii] = (f16)e;
            else if (q == 1) ecd   [(size_t)bh * N_ * N_ + ii * N_ + jj] = e;
            else             eef16 [(size_t)bh * N_ * N_ + ii * N_ + jj] = (f16)e;
        }
}

// ---------------------------------------------------------------------------
// Kernel 3 (dominant), MFMA f16.
// Changes vs previous round:
//  * A-fragments (U16 = f16(eCD * v2col)) built DIRECTLY in registers from
//    global ecd (L2-resident) x v2k LDS chunk -- the 36.9 KB `us` buffer is
//    gone. LDS: 62464 -> 25600 B. With __launch_bounds__(256,4) (VGPR<=128)
//    occupancy goes 2 -> 4 blocks/CU.
//  * kt loop split 2-way across grid.z (816 -> 1632 blocks) so the grid can
//    actually FILL 4 blocks/CU. Halves accumulate to disjoint partial
//    buffers (linear in kt); finalize sums them.
// ---------------------------------------------------------------------------
__global__ __launch_bounds__(256, 4) void triplet_mfma_kernel(
        const f16*  __restrict__ eabt,   // [bh][j][i]
        const float* __restrict__ ecd,   // [bh][i][k]
        const f16*  __restrict__ eef,    // [bh][j][k]
        const float* __restrict__ v1,    // [bh][n][64]
        const float* __restrict__ v2,    // [bh][n][64]
        float* __restrict__ num0,        // [bh][i][68] partial (kt 0..2)
        float* __restrict__ num1) {      // [bh][i][68] partial (kt 3..5)
    __shared__ __align__(16) unsigned char smem_raw[25600];
    f16*   es   = (f16*)smem_raw;                    // 64*PIT f16 = 9216 B
    f16*   abts = es + 64 * PIT;                     // 64*PIT f16 = 9216 B
    float* v1s  = (float*)(smem_raw + 18432);        // 384*4 f32  = 6144 B
    float* v2k  = (float*)(smem_raw + 24576);        // 4*64 f32   = 1024 B

    const int tid  = threadIdx.x;
    const int lane = tid & 63;
    const int w    = tid >> 6;        // wave id = d slot
    const int quad = lane >> 4;
    const int lr   = lane & 15;
    const int i0 = blockIdx.x * 64;
    const int dg = blockIdx.y;        // 0..16
    const int zz = blockIdx.z;
    const int bh    = zz & 7;
    const int split = zz >> 3;        // 0 or 1 -> kt half
    const int dd = dg * 4 + w;        // 0..67 (>=64: denominator)

    const f16*   eabtb = eabt + (size_t)bh * N_ * N_;
    const float* ecdb  = ecd  + (size_t)bh * N_ * N_;
    const f16*   eefb  = eef  + (size_t)bh * N_ * N_;
    const float* v1b   = v1 + (size_t)bh * N_ * D_;
    const float* v2b   = v2 + (size_t)bh * N_ * D_;
    float* numout = split ? num1 : num0;

    // stage v1 columns for the 4 d-slots: v1s[j*4 + c]
#pragma unroll
    for (int it = 0; it < 6; ++it) {
        const int id = it * 256 + tid;          // 0..1535
        const int j = id >> 2, c = id & 3;
        const int d2 = dg * 4 + c;
        v1s[id] = (d2 < 64) ? v1b[j * 64 + d2] : 1.0f;
    }

    float numacc[16];
#pragma unroll
    for (int r = 0; r < 16; ++r) numacc[r] = 0.f;

    const int ktbeg = split * 3;
    for (int kt = ktbeg; kt < ktbeg + 3; ++kt) {
        const int k0 = kt * 64;
        __syncthreads();                 // prior readers of v2k done
        // stage v2 chunk: v2k[c*64 + k]
        {
            const int c = tid >> 6, k = tid & 63;
            const int d2 = dg * 4 + c;
            v2k[c * 64 + k] = (d2 < 64) ? v2b[(k0 + k) * 64 + d2] : 1.0f;
        }
        __syncthreads();
        // this wave's v2 values for its quad's k-chunks: [ks][half]
        float4 v2a[2][2];
#pragma unroll
        for (int ks = 0; ks < 2; ++ks) {
            v2a[ks][0] = *(const float4*)&v2k[w * 64 + ks * 32 + quad * 8];
            v2a[ks][1] = *(const float4*)&v2k[w * 64 + ks * 32 + quad * 8 + 4];
        }
        // A-frags built in registers: af[isub][ks] lane elem e =
        //   f16( ecd[i0+isub*16+lr][k0 + ks*32 + quad*8 + e] * v2[.][dd] )
        f16x8 af[4][2];
#pragma unroll
        for (int isub = 0; isub < 4; ++isub) {
            const float* rowp = ecdb + (i0 + isub * 16 + lr) * N_ + k0 + quad * 8;
#pragma unroll
            for (int ks = 0; ks < 2; ++ks) {
                const float4 c0 = *(const float4*)(rowp + ks * 32);
                const float4 c1 = *(const float4*)(rowp + ks * 32 + 4);
                union { f16 h[8]; f16x8 v; } pk;
                pk.h[0] = (f16)(c0.x * v2a[ks][0].x);
                pk.h[1] = (f16)(c0.y * v2a[ks][0].y);
                pk.h[2] = (f16)(c0.z * v2a[ks][0].z);
                pk.h[3] = (f16)(c0.w * v2a[ks][0].w);
                pk.h[4] = (f16)(c1.x * v2a[ks][1].x);
                pk.h[5] = (f16)(c1.y * v2a[ks][1].y);
                pk.h[6] = (f16)(c1.z * v2a[ks][1].z);
                pk.h[7] = (f16)(c1.w * v2a[ks][1].w);
                af[isub][ks] = pk.v;
            }
        }

        for (int jt = 0; jt < 6; ++jt) {
            const int j0 = jt * 64;
            __syncthreads();             // prior readers of es/abts done
#pragma unroll
            for (int it = 0; it < 2; ++it) {
                const int row = it * 32 + (tid >> 3);
                const int blk = tid & 7;
                *(uint4*)(es   + row * PIT + blk * 8) =
                    *(const uint4*)(eefb  + (j0 + row) * N_ + k0 + blk * 8);
                *(uint4*)(abts + row * PIT + blk * 8) =
                    *(const uint4*)(eabtb + (j0 + row) * N_ + i0 + blk * 8);
            }
            __syncthreads();
            // B-frags (shared across the 4 i-subtiles)
            f16x8 bf[4][2];
#pragma unroll
            for (int js = 0; js < 4; ++js)
#pragma unroll
                for (int ks = 0; ks < 2; ++ks)
                    bf[js][ks] = *(const f16x8*)(es + (js * 16 + lr) * PIT + (ks * 4 + quad) * 8);
            // MFMA + immediate fold of the partial R tile
#pragma unroll
            for (int js = 0; js < 4; ++js) {
                const float v1v = v1s[(j0 + js * 16 + lr) * 4 + w];
#pragma unroll
                for (int isub = 0; isub < 4; ++isub) {
                    f32x4 t = {0.f, 0.f, 0.f, 0.f};
                    t = __builtin_amdgcn_mfma_f32_16x16x32_f16(af[isub][0], bf[js][0], t, 0, 0, 0);
                    t = __builtin_amdgcn_mfma_f32_16x16x32_f16(af[isub][1], bf[js][1], t, 0, 0, 0);
                    const f16x4 ab = *(const f16x4*)(abts + (js * 16 + lr) * PIT +
                                                     isub * 16 + quad * 4);
#pragma unroll
                    for (int q = 0; q < 4; ++q)
                        numacc[isub * 4 + q] += (float)ab[q] * (v1v * t[q]);
                }
            }
        }
    }
    // reduce the j-residues (low 4 lane bits) and write
#pragma unroll
    for (int r = 0; r < 16; ++r) {
        float v = numacc[r];
        v += __shfl_xor(v, 1);
        v += __shfl_xor(v, 2);
        v += __shfl_xor(v, 4);
        v += __shfl_xor(v, 8);
        numacc[r] = v;
    }
    if (lr == 0) {
#pragma unroll
        for (int r = 0; r < 16; ++r) {
            const int i = (r >> 2) * 16 + quad * 4 + (r & 3);
            numout[((size_t)bh * N_ + i0 + i) * 68 + dd] = numacc[r];
        }
    }
}

// ---------------------------------------------------------------------------
// Kernel 4: out[b,n,h*64+d] = (num0+num1)[bh,n,d] / (num0+num1)[bh,n,64]
// ---------------------------------------------------------------------------
__global__ __launch_bounds__(256) void finalize_kernel(const float* __restrict__ num0,
                                                       const float* __restrict__ num1,
                                                       float* __restrict__ out) {
    const int o = blockIdx.x * 256 + threadIdx.x;
    const int b = o / (N_ * C_);
    const int rem = o - b * (N_ * C_);
    const int n = rem >> 8;
    const int cc = rem & 255;
    const int h = cc >> 6, d = cc & 63;
    const size_t base = (((size_t)b * H_ + h) * N_ + n) * 68;
    const float nmr = num0[base + d]  + num1[base + d];
    const float dnr = num0[base + 64] + num1[base + 64];
    out[o] = nmr / dnr;
}

extern "C" void kernel_launch(void* const* d_in, const int* in_sizes, int n_in,
                              void* d_out, int out_size, void* d_ws, size_t ws_size,
                              hipStream_t stream) {
    const float* x = (const float*)d_in[0];
    const float* W = (const float*)d_in[1];
    float* ws    = (float*)d_ws;
    float* proj  = ws;                         // 5*TSZ f32
    float* ecd   = ws + 5 * TSZ;               // ESZ f32
    float* num1  = ecd + ESZ;                  // NWSLICE f32 (kt 3..5 partial)
    f16*   eabt  = (f16*)(num1 + NWSLICE);     // ESZ f16
    f16*   eef   = eabt + ESZ;                 // ESZ f16
    // num0 reuses proj slots 0-1 (a,b) -- dead after logits_kernel.
    // NWSLICE (208896) < 2*TSZ (393216), so it fits without touching v1/v2.
    float* num0  = ws;
    // total ws usage unchanged: ~14.2 MB

    proj_kernel<<<dim3(12, 20), 256, 0, stream>>>(x, W, proj);
    logits_kernel<<<dim3(6, 6, 24), 256, 0, stream>>>(proj, eabt, ecd, eef);
    triplet_mfma_kernel<<<dim3(6, 17, 16), 256, 0, stream>>>(
        eabt, ecd, eef, proj + 3 * TSZ, proj + 4 * TSZ, num0, num1);
    finalize_kernel<<<dim3(768), 256, 0, stream>>>(num0, num1, (float*)d_out);
}

// Round 2
// 307.938 us; speedup vs baseline: 1.6947x; 1.6947x over previous
//
#include <hip/hip_runtime.h>
#include <math.h>

#define B_  2
#define N_  384
#define C_  256
#define H_  4
#define D_  64
#define NBH (B_*H_)            // 8
#define TSZ (NBH*N_*D_)        // 196608 floats per projected tensor [bh][n][d]
#define ESZ (NBH*N_*N_)        // 1179648 elems per logit matrix [bh][i][j]
#define SCALE 0.125f           // D^-0.5
#define PIT 72                 // padded LDS pitch in f16 (144B) -> 2-way max bank alias
#define NWSLICE (NBH*N_*68)    // 208896 floats per numw partial

typedef _Float16 f16;
typedef f16  f16x8 __attribute__((ext_vector_type(8)));
typedef f16  f16x4 __attribute__((ext_vector_type(4)));
typedef float f32x4 __attribute__((ext_vector_type(4)));

// ---------------------------------------------------------------------------
// Kernel 1: projection (unchanged). proj[t][bh][n][d], t in {a,b,c,v1,v2}, f32.
// ---------------------------------------------------------------------------
__global__ __launch_bounds__(256) void proj_kernel(const float* __restrict__ x,
                                                   const float* __restrict__ W,
                                                   float* __restrict__ proj) {
    __shared__ float Xs[32][68];
    __shared__ float Ws[32][68];
    const int tid = threadIdx.x;
    const int tx = tid & 15, ty = tid >> 4;
    const int m0 = blockIdx.x * 64;
    const int c0 = blockIdx.y * 64;
    const int t  = c0 >> 8;
    const int wbase = ((t >= 3) ? (t + 3) : t) * 256;

    float acc[4][4] = {{0.f}};
    for (int k0 = 0; k0 < 256; k0 += 32) {
        __syncthreads();
#pragma unroll
        for (int l = 0; l < 8; ++l) {
            const int idx = l * 256 + tid;
            const int mi = idx >> 5, kk = idx & 31;
            Xs[kk][mi] = x[(m0 + mi) * 256 + k0 + kk];
            const int rem = (c0 + mi) & 255;
            Ws[kk][mi] = W[(wbase + rem) * 256 + k0 + kk];
        }
        __syncthreads();
#pragma unroll
        for (int kk = 0; kk < 32; ++kk) {
            const float4 xf = *(const float4*)&Xs[kk][ty * 4];
            const float4 wf = *(const float4*)&Ws[kk][tx * 4];
            const float xa[4] = {xf.x, xf.y, xf.z, xf.w};
            const float wa[4] = {wf.x, wf.y, wf.z, wf.w};
#pragma unroll
            for (int q = 0; q < 4; ++q)
#pragma unroll
                for (int p = 0; p < 4; ++p)
                    acc[q][p] += xa[q] * wa[p];
        }
    }
#pragma unroll
    for (int q = 0; q < 4; ++q) {
        const int r = m0 + ty * 4 + q;
        const int b = r / N_;
        const int n = r - b * N_;
#pragma unroll
        for (int p = 0; p < 4; ++p) {
            const int rem = (c0 + tx * 4 + p) & 255;
            const int h = rem >> 6, d = rem & 63;
            proj[t * TSZ + ((b * H_ + h) * N_ + n) * D_ + d] = acc[q][p];
        }
    }
}

// ---------------------------------------------------------------------------
// Kernel 2: exp-logit matrices, mixed-dtype outputs (unchanged).
// ---------------------------------------------------------------------------
__global__ __launch_bounds__(256) void logits_kernel(const float* __restrict__ proj,
                                                     f16* __restrict__ eabt16,
                                                     float* __restrict__ ecd,
                                                     f16* __restrict__ eef16) {
    __shared__ float Xs[32][68];
    __shared__ float Ys[32][68];
    const int tid = threadIdx.x;
    const int tx = tid & 15, ty = tid >> 4;
    const int i0 = blockIdx.x * 64, j0 = blockIdx.y * 64;
    const int q  = blockIdx.z >> 3;
    const int bh = blockIdx.z & 7;
    const int xt = q;
    const int yt = (q == 2) ? 0 : (q + 1);
    const float* Xp = proj + xt * TSZ + bh * N_ * D_;
    const float* Yp = proj + yt * TSZ + bh * N_ * D_;

    float acc[4][4] = {{0.f}};
    for (int k0 = 0; k0 < 64; k0 += 32) {
        __syncthreads();
#pragma unroll
        for (int l = 0; l < 8; ++l) {
            const int idx = l * 256 + tid;
            const int mi = idx >> 5, kk = idx & 31;
            Xs[kk][mi] = Xp[(i0 + mi) * 64 + k0 + kk];
            Ys[kk][mi] = Yp[(j0 + mi) * 64 + k0 + kk];
        }
        __syncthreads();
#pragma unroll
        for (int kk = 0; kk < 32; ++kk) {
            const float4 xf = *(const float4*)&Xs[kk][ty * 4];
            const float4 yf = *(const float4*)&Ys[kk][tx * 4];
            const float xa[4] = {xf.x, xf.y, xf.z, xf.w};
            const float ya[4] = {yf.x, yf.y, yf.z, yf.w};
#pragma unroll
            for (int qq = 0; qq < 4; ++qq)
#pragma unroll
                for (int p = 0; p < 4; ++p)
                    acc[qq][p] += xa[qq] * ya[p];
        }
    }
#pragma unroll
    for (int qq = 0; qq < 4; ++qq)
#pragma unroll
        for (int p = 0; p < 4; ++p) {
            const float e = expf(acc[qq][p] * SCALE);
            const int ii = i0 + ty * 4 + qq;
            const int jj = j0 + tx * 4 + p;
            if (q == 0)      eabt16[(size_t)bh * N_ * N_ + jj * N_ + ii] = (f16)e;
            else if (q == 1) ecd   [(size_t)bh * N_ * N_ + ii * N_ + jj] = e;
            else             eef16 [(size_t)bh * N_ * N_ + ii * N_ + jj] = (f16)e;
        }
}

// ---------------------------------------------------------------------------
// Kernel 3 (dominant), MFMA f16.
// Round-2 changes:
//  * __launch_bounds__(256) -- NO min-occupancy arg. Round 1's (256,4)
//    forced a 64-VGPR arch split and spilled ~1.7 GB of scratch traffic
//    (FETCH/WRITE both ~850 MB, symmetric = spill signature).
//  * bf loaded per-js inside the loop (not pre-loaded [4][2]) -- trims
//    ~24 live VGPRs so the natural allocation lands near round-0's 96.
//  * Keeps round-1 structure: register-built A-frags (no `us` LDS buffer,
//    LDS 25600 B) + 2-way kt split across grid.z with partial buffers.
// ---------------------------------------------------------------------------
__global__ __launch_bounds__(256) void triplet_mfma_kernel(
        const f16*  __restrict__ eabt,   // [bh][j][i]
        const float* __restrict__ ecd,   // [bh][i][k]
        const f16*  __restrict__ eef,    // [bh][j][k]
        const float* __restrict__ v1,    // [bh][n][64]
        const float* __restrict__ v2,    // [bh][n][64]
        float* __restrict__ num0,        // [bh][i][68] partial (kt 0..2)
        float* __restrict__ num1) {      // [bh][i][68] partial (kt 3..5)
    __shared__ __align__(16) unsigned char smem_raw[25600];
    f16*   es   = (f16*)smem_raw;                    // 64*PIT f16 = 9216 B
    f16*   abts = es + 64 * PIT;                     // 64*PIT f16 = 9216 B
    float* v1s  = (float*)(smem_raw + 18432);        // 384*4 f32  = 6144 B
    float* v2k  = (float*)(smem_raw + 24576);        // 4*64 f32   = 1024 B

    const int tid  = threadIdx.x;
    const int lane = tid & 63;
    const int w    = tid >> 6;        // wave id = d slot
    const int quad = lane >> 4;
    const int lr   = lane & 15;
    const int i0 = blockIdx.x * 64;
    const int dg = blockIdx.y;        // 0..16
    const int zz = blockIdx.z;
    const int bh    = zz & 7;
    const int split = zz >> 3;        // 0 or 1 -> kt half
    const int dd = dg * 4 + w;        // 0..67 (>=64: denominator)

    const f16*   eabtb = eabt + (size_t)bh * N_ * N_;
    const float* ecdb  = ecd  + (size_t)bh * N_ * N_;
    const f16*   eefb  = eef  + (size_t)bh * N_ * N_;
    const float* v1b   = v1 + (size_t)bh * N_ * D_;
    const float* v2b   = v2 + (size_t)bh * N_ * D_;
    float* numout = split ? num1 : num0;

    // stage v1 columns for the 4 d-slots: v1s[j*4 + c]
#pragma unroll
    for (int it = 0; it < 6; ++it) {
        const int id = it * 256 + tid;          // 0..1535
        const int j = id >> 2, c = id & 3;
        const int d2 = dg * 4 + c;
        v1s[id] = (d2 < 64) ? v1b[j * 64 + d2] : 1.0f;
    }

    float numacc[16];
#pragma unroll
    for (int r = 0; r < 16; ++r) numacc[r] = 0.f;

    const int ktbeg = split * 3;
    for (int kt = ktbeg; kt < ktbeg + 3; ++kt) {
        const int k0 = kt * 64;
        __syncthreads();                 // prior readers of v2k done
        // stage v2 chunk: v2k[c*64 + k]
        {
            const int c = tid >> 6, k = tid & 63;
            const int d2 = dg * 4 + c;
            v2k[c * 64 + k] = (d2 < 64) ? v2b[(k0 + k) * 64 + d2] : 1.0f;
        }
        __syncthreads();
        // this wave's v2 values for its quad's k-chunks: [ks][half]
        float4 v2a[2][2];
#pragma unroll
        for (int ks = 0; ks < 2; ++ks) {
            v2a[ks][0] = *(const float4*)&v2k[w * 64 + ks * 32 + quad * 8];
            v2a[ks][1] = *(const float4*)&v2k[w * 64 + ks * 32 + quad * 8 + 4];
        }
        // A-frags built in registers: af[isub][ks] lane elem e =
        //   f16( ecd[i0+isub*16+lr][k0 + ks*32 + quad*8 + e] * v2[.][dd] )
        f16x8 af[4][2];
#pragma unroll
        for (int isub = 0; isub < 4; ++isub) {
            const float* rowp = ecdb + (i0 + isub * 16 + lr) * N_ + k0 + quad * 8;
#pragma unroll
            for (int ks = 0; ks < 2; ++ks) {
                const float4 c0 = *(const float4*)(rowp + ks * 32);
                const float4 c1 = *(const float4*)(rowp + ks * 32 + 4);
                union { f16 h[8]; f16x8 v; } pk;
                pk.h[0] = (f16)(c0.x * v2a[ks][0].x);
                pk.h[1] = (f16)(c0.y * v2a[ks][0].y);
                pk.h[2] = (f16)(c0.z * v2a[ks][0].z);
                pk.h[3] = (f16)(c0.w * v2a[ks][0].w);
                pk.h[4] = (f16)(c1.x * v2a[ks][1].x);
                pk.h[5] = (f16)(c1.y * v2a[ks][1].y);
                pk.h[6] = (f16)(c1.z * v2a[ks][1].z);
                pk.h[7] = (f16)(c1.w * v2a[ks][1].w);
                af[isub][ks] = pk.v;
            }
        }

        for (int jt = 0; jt < 6; ++jt) {
            const int j0 = jt * 64;
            __syncthreads();             // prior readers of es/abts done
#pragma unroll
            for (int it = 0; it < 2; ++it) {
                const int row = it * 32 + (tid >> 3);
                const int blk = tid & 7;
                *(uint4*)(es   + row * PIT + blk * 8) =
                    *(const uint4*)(eefb  + (j0 + row) * N_ + k0 + blk * 8);
                *(uint4*)(abts + row * PIT + blk * 8) =
                    *(const uint4*)(eabtb + (j0 + row) * N_ + i0 + blk * 8);
            }
            __syncthreads();
            // MFMA + immediate fold of the partial R tile.
            // bf loaded per-js (8 live VGPRs) instead of a [4][2] array.
#pragma unroll
            for (int js = 0; js < 4; ++js) {
                const f16x8 bf0 = *(const f16x8*)(es + (js * 16 + lr) * PIT + quad * 8);
                const f16x8 bf1 = *(const f16x8*)(es + (js * 16 + lr) * PIT + (4 + quad) * 8);
                const float v1v = v1s[(j0 + js * 16 + lr) * 4 + w];
#pragma unroll
                for (int isub = 0; isub < 4; ++isub) {
                    f32x4 t = {0.f, 0.f, 0.f, 0.f};
                    t = __builtin_amdgcn_mfma_f32_16x16x32_f16(af[isub][0], bf0, t, 0, 0, 0);
                    t = __builtin_amdgcn_mfma_f32_16x16x32_f16(af[isub][1], bf1, t, 0, 0, 0);
                    const f16x4 ab = *(const f16x4*)(abts + (js * 16 + lr) * PIT +
                                                     isub * 16 + quad * 4);
#pragma unroll
                    for (int q = 0; q < 4; ++q)
                        numacc[isub * 4 + q] += (float)ab[q] * (v1v * t[q]);
                }
            }
        }
    }
    // reduce the j-residues (low 4 lane bits) and write
#pragma unroll
    for (int r = 0; r < 16; ++r) {
        float v = numacc[r];
        v += __shfl_xor(v, 1);
        v += __shfl_xor(v, 2);
        v += __shfl_xor(v, 4);
        v += __shfl_xor(v, 8);
        numacc[r] = v;
    }
    if (lr == 0) {
#pragma unroll
        for (int r = 0; r < 16; ++r) {
            const int i = (r >> 2) * 16 + quad * 4 + (r & 3);
            numout[((size_t)bh * N_ + i0 + i) * 68 + dd] = numacc[r];
        }
    }
}

// ---------------------------------------------------------------------------
// Kernel 4: out[b,n,h*64+d] = (num0+num1)[bh,n,d] / (num0+num1)[bh,n,64]
// ---------------------------------------------------------------------------
__global__ __launch_bounds__(256) void finalize_kernel(const float* __restrict__ num0,
                                                       const float* __restrict__ num1,
                                                       float* __restrict__ out) {
    const int o = blockIdx.x * 256 + threadIdx.x;
    const int b = o / (N_ * C_);
    const int rem = o - b * (N_ * C_);
    const int n = rem >> 8;
    const int cc = rem & 255;
    const int h = cc >> 6, d = cc & 63;
    const size_t base = (((size_t)b * H_ + h) * N_ + n) * 68;
    const float nmr = num0[base + d]  + num1[base + d];
    const float dnr = num0[base + 64] + num1[base + 64];
    out[o] = nmr / dnr;
}

extern "C" void kernel_launch(void* const* d_in, const int* in_sizes, int n_in,
                              void* d_out, int out_size, void* d_ws, size_t ws_size,
                              hipStream_t stream) {
    const float* x = (const float*)d_in[0];
    const float* W = (const float*)d_in[1];
    float* ws    = (float*)d_ws;
    float* proj  = ws;                         // 5*TSZ f32
    float* ecd   = ws + 5 * TSZ;               // ESZ f32
    float* num1  = ecd + ESZ;                  // NWSLICE f32 (kt 3..5 partial)
    f16*   eabt  = (f16*)(num1 + NWSLICE);     // ESZ f16
    f16*   eef   = eabt + ESZ;                 // ESZ f16
    // num0 reuses proj slots 0-1 (a,b) -- dead after logits_kernel.
    // NWSLICE (208896) < 2*TSZ (393216), so it fits without touching v1/v2.
    float* num0  = ws;
    // total ws usage unchanged: ~14.2 MB

    proj_kernel<<<dim3(12, 20), 256, 0, stream>>>(x, W, proj);
    logits_kernel<<<dim3(6, 6, 24), 256, 0, stream>>>(proj, eabt, ecd, eef);
    triplet_mfma_kernel<<<dim3(6, 17, 16), 256, 0, stream>>>(
        eabt, ecd, eef, proj + 3 * TSZ, proj + 4 * TSZ, num0, num1);
    finalize_kernel<<<dim3(768), 256, 0, stream>>>(num0, num1, (float*)d_out);
}